// Round 6
// baseline (276.493 us; speedup 1.0000x reference)
//
#include <hip/hip_runtime.h>
#include <hip/hip_bf16.h>
#include <stdint.h>

#define B_ROWS 32768
#define DIM    1024
#define KACT   102       // int(1024*0.1)
#define KPAD   104
#define KP2    53        // 52 bf16-pairs + 1 pad (odd -> conflict-free LDS rows)

typedef short bf16x8 __attribute__((ext_vector_type(8)));
typedef unsigned short u16x8 __attribute__((ext_vector_type(8)));
typedef float f32x4  __attribute__((ext_vector_type(4)));

__device__ __forceinline__ unsigned short f2bf(float f) {
  union { float f; unsigned u; } v; v.f = f;
  unsigned u = v.u;
  unsigned r = u + 0x7fffu + ((u >> 16) & 1u);   // RNE
  return (unsigned short)(r >> 16);
}
__device__ __forceinline__ float bfasf(unsigned hi16) {   // f32 from top-16 bits
  union { unsigned u; float f; } v; v.u = hi16;
  return v.f;
}

// async global->LDS, 16B per lane
#define GLDS(g, l) __builtin_amdgcn_global_load_lds( \
    (__attribute__((address_space(1))) void*)(g),    \
    (__attribute__((address_space(3))) void*)(l), 16, 0, 0)

// ---------------------------------------------------------------------------
// K1: merged conv + w1t.
// blocks 0..511: x fp32 -> bf16 (xb) + per-column partial sum|x| (f32).
// blocks 512..767: w1 [K][N] fp32 -> w1t [N][K] bf16 (transpose+convert).
// ---------------------------------------------------------------------------
__global__ __launch_bounds__(256) void k_convw(
    const float* __restrict__ x, const float* __restrict__ w1,
    unsigned short* __restrict__ xb, unsigned short* __restrict__ w1t,
    float* __restrict__ partial) {
  const int t = threadIdx.x;
  if (blockIdx.x < 512) {
    const int c0 = t * 4;
    const size_t base = (size_t)blockIdx.x * 64 * DIM;
    float s0 = 0.f, s1 = 0.f, s2 = 0.f, s3 = 0.f;
    #pragma unroll 4
    for (int j = 0; j < 64; ++j) {
      size_t off = base + (size_t)j * DIM + c0;
      float4 v = *(const float4*)(x + off);
      s0 += fabsf(v.x); s1 += fabsf(v.y); s2 += fabsf(v.z); s3 += fabsf(v.w);
      ushort4 o;
      o.x = f2bf(v.x); o.y = f2bf(v.y); o.z = f2bf(v.z); o.w = f2bf(v.w);
      *(ushort4*)(xb + off) = o;
    }
    float4 p; p.x = s0; p.y = s1; p.z = s2; p.w = s3;
    *(float4*)(partial + (size_t)blockIdx.x * DIM + c0) = p;
  } else {
    __shared__ unsigned short tile[64][65];
    const int b  = blockIdx.x - 512;
    const int bx = b & 15;
    const int by = b >> 4;
    for (int e = t; e < 64 * 64; e += 256) {
      int r = e >> 6, c = e & 63;
      tile[r][c] = f2bf(w1[(size_t)(by * 64 + r) * DIM + bx * 64 + c]);
    }
    __syncthreads();
    for (int e = t; e < 64 * 64; e += 256) {
      int c = e >> 6, r = e & 63;
      w1t[(size_t)(bx * 64 + c) * DIM + by * 64 + r] = tile[r][c];
    }
  }
}

// ---------------------------------------------------------------------------
// K2: reduce 512 partials -> 8 k-slice partials (deterministic).
// ---------------------------------------------------------------------------
__global__ __launch_bounds__(128) void k_reduce1(const float* __restrict__ partial,
                                                 float* __restrict__ p2) {
  const int c  = (blockIdx.x & 7) * 128 + threadIdx.x;
  const int ks = blockIdx.x >> 3;
  float s = 0.f;
  #pragma unroll 8
  for (int p = ks * 64; p < ks * 64 + 64; ++p) s += partial[(size_t)p * DIM + c];
  p2[ks * DIM + c] = s;
}

// ---------------------------------------------------------------------------
// K3: rank + compact only. 1 block x 1024 threads. Rank arithmetic identical
// to all prior passing rounds (f64 sum of 8 f32 slices, ks-order 0..7,
// tie-break lower index == lax.top_k).
// ---------------------------------------------------------------------------
__global__ __launch_bounds__(1024) void k_sel(const float* __restrict__ p2,
                                              int* __restrict__ act,
                                              int* __restrict__ cmap) {
  __shared__ double sv[DIM];
  __shared__ int wcnt[16];
  const int d = threadIdx.x;
  {
    double s = 0.0;
    #pragma unroll
    for (int ks = 0; ks < 8; ++ks) s += (double)p2[ks * DIM + d];
    sv[d] = s;
  }
  __syncthreads();
  const double sd = sv[d];
  int rank = 0;
  for (int j = 0; j < DIM; ++j) {
    double s = sv[j];
    rank += (s > sd || (s == sd && j < d)) ? 1 : 0;
  }
  const int f = (rank < KACT) ? 1 : 0;
  unsigned long long m = __ballot(f != 0);
  const int lane = d & 63, w = d >> 6;
  if (lane == 0) wcnt[w] = __popcll(m);
  __syncthreads();
  int off = 0;
  for (int i = 0; i < w; ++i) off += wcnt[i];
  int pos = off + __popcll(m & ((1ull << lane) - 1ull));
  cmap[d] = f ? pos : -1;
  if (f) act[pos] = d;
}

// ---------------------------------------------------------------------------
// K5: r1 = x @ w1 bf16 MFMA. 256x256 tile, 8 waves (2x4), BK=32, 4-slot LDS
// ring, counted-vmcnt pipeline (stage kt+2 while computing kt), setprio,
// XOR bank swizzle. NEW: one phase per K-tile -> 32 MFMA per barrier-pair,
// 64 barriers/block (was 128).
// ---------------------------------------------------------------------------
#define VMW4 asm volatile("s_waitcnt vmcnt(4)" ::: "memory")
#define VMW0 asm volatile("s_waitcnt vmcnt(0)" ::: "memory")
#define NOP_ (void)0

#define STAGE(KT) do { \
  GLDS(Abase + (size_t)sr0 * 1024 + (KT) * 32 + sc0 * 8, &Asl[((KT)&3)*8192 + p0*8]); \
  GLDS(Abase + (size_t)sr1 * 1024 + (KT) * 32 + sc1 * 8, &Asl[((KT)&3)*8192 + p1*8]); \
  GLDS(Bbase + (size_t)sr0 * 1024 + (KT) * 32 + sc0 * 8, &Bsl[((KT)&3)*8192 + p0*8]); \
  GLDS(Bbase + (size_t)sr1 * 1024 + (KT) * 32 + sc1 * 8, &Bsl[((KT)&3)*8192 + p1*8]); \
} while (0)

#define PH(SLOT, STAGE_STMT, WAIT_STMT) do { \
  _Pragma("unroll") for (int i = 0; i < 8; ++i) \
    areg[i] = *(const bf16x8*)(&Asl[(SLOT)*8192 + aoff0 + i * 512]); \
  _Pragma("unroll") for (int i = 0; i < 4; ++i) \
    breg[i] = *(const bf16x8*)(&Bsl[(SLOT)*8192 + boff0 + i * 512]); \
  STAGE_STMT; \
  WAIT_STMT; \
  __builtin_amdgcn_s_barrier(); \
  __builtin_amdgcn_s_setprio(1); \
  _Pragma("unroll") for (int mi = 0; mi < 8; ++mi) \
  _Pragma("unroll") for (int ni = 0; ni < 4; ++ni) \
    acc[mi][ni] = __builtin_amdgcn_mfma_f32_16x16x32_bf16(areg[mi], breg[ni], acc[mi][ni], 0, 0, 0); \
  __builtin_amdgcn_s_setprio(0); \
  __builtin_amdgcn_s_barrier(); \
} while (0)

__global__ __launch_bounds__(512, 2) void k_gemm_r1(
    const unsigned short* __restrict__ A,
    const unsigned short* __restrict__ Bt,
    float* __restrict__ C) {
  __shared__ unsigned short Asl[4 * 8192];   // 4 slots x [256 rows][32 k] bf16
  __shared__ unsigned short Bsl[4 * 8192];

  const int t    = threadIdx.x;
  const int lane = t & 63;
  const int wave = t >> 6;
  const int wm   = wave >> 2;
  const int wn   = wave & 3;
  const int la   = lane & 15;
  const int kg   = lane >> 4;
  const int kgx  = kg ^ ((la >> 1) & 3);   // physical k-chunk after swizzle

  // XCD-bijective swizzle: 512 blocks, 64 contiguous tiles per XCD
  const int swz  = (blockIdx.x & 7) * 64 + (blockIdx.x >> 3);
  const int brow = swz >> 2;
  const int bcol = swz & 3;

  const unsigned short* Abase = A  + (size_t)brow * 256 * 1024;
  const unsigned short* Bbase = Bt + (size_t)bcol * 256 * 1024;

  // staging: physical chunk p holds logical chunk q = p ^ ((p>>3)&3)
  const int p0 = t, p1 = t + 512;
  const int q0 = p0 ^ ((p0 >> 3) & 3);
  const int q1 = p1 ^ ((p1 >> 3) & 3);
  const int sr0 = q0 >> 2, sc0 = q0 & 3;
  const int sr1 = q1 >> 2, sc1 = q1 & 3;

  const int aoff0 = (wm * 128 + la) * 32 + kgx * 8;
  const int boff0 = (wn * 64  + la) * 32 + kgx * 8;

  f32x4 acc[8][4];
  #pragma unroll
  for (int mi = 0; mi < 8; ++mi)
    #pragma unroll
    for (int ni = 0; ni < 4; ++ni)
      acc[mi][ni] = (f32x4){0.f, 0.f, 0.f, 0.f};

  bf16x8 areg[8], breg[4];

  STAGE(0); STAGE(1);
  VMW4;
  __builtin_amdgcn_s_barrier();

  for (int kt4 = 0; kt4 < 28; kt4 += 4) {
    PH(0, STAGE(kt4 + 2), VMW4);
    PH(1, STAGE(kt4 + 3), VMW4);
    PH(2, STAGE(kt4 + 4), VMW4);
    PH(3, STAGE(kt4 + 5), VMW4);
  }
  PH(0, STAGE(30), VMW4);   // kt=28
  PH(1, STAGE(31), VMW4);   // kt=29
  PH(2, NOP_, VMW0);        // kt=30 (final drain)
  PH(3, NOP_, NOP_);        // kt=31

  // C/D layout: col = lane&15, row = (lane>>4)*4 + reg
  const int orow0 = brow * 256 + wm * 128 + (lane >> 4) * 4;
  const int ocol0 = bcol * 256 + wn * 64 + la;
  #pragma unroll
  for (int mi = 0; mi < 8; ++mi)
    #pragma unroll
    for (int ni = 0; ni < 4; ++ni)
      #pragma unroll
      for (int r = 0; r < 4; ++r)
        C[(size_t)(orow0 + mi * 16 + r) * DIM + ocol0 + ni * 16] = acc[mi][ni][r];
}

// ---------------------------------------------------------------------------
// K6: r2/r3. 512 blocks x 512 thr, 64 rows/block in 4 chunks of 16 rows.
// Streaming, no reg-prefetch (TLP hides latency at 2 blocks/CU).
// W2/W3 gathered in-kernel from global via act (L2-hot across blocks),
// packed bf16-pairs [j][i2] u32, row stride 53.  LDS ~68.6 KB.
// ---------------------------------------------------------------------------
__global__ __launch_bounds__(512, 4) void k_r23(
    const unsigned short* __restrict__ xb,
    const float* __restrict__ w2,
    const float* __restrict__ w3,
    const int* __restrict__ act,
    const int* __restrict__ cmap,
    float* __restrict__ out2,
    float* __restrict__ out3) {
  __shared__ unsigned int Wp2[KPAD * KP2];
  __shared__ unsigned int Wp3[KPAD * KP2];
  __shared__ float xs [16 * KPAD];
  __shared__ float r2s[16 * KPAD];
  __shared__ float r3s[16 * KPAD];
  __shared__ int   cms[DIM];
  __shared__ int   acts[KACT];
  const int t    = threadIdx.x;
  const int row0 = blockIdx.x * 64;

  if (t < KACT) acts[t] = act[t];
  for (int e = t; e < DIM; e += 512) cms[e] = cmap[e];
  if (t < 16) { xs[t * KPAD + 102] = 0.f; xs[t * KPAD + 103] = 0.f; }
  __syncthreads();

  // gather W tiles: Wp[j*KP2 + i2] = {w[act[2i2]][act[j]], w[act[2i2+1]][act[j]]}
  for (int e = t; e < KPAD * 52; e += 512) {
    int i2 = e / KPAD, j = e - i2 * KPAD;
    float lo2 = 0.f, hi2 = 0.f, lo3 = 0.f, hi3 = 0.f;
    if (j < KACT && i2 < 51) {
      int cj = acts[j];
      size_t o0 = (size_t)acts[2 * i2] * DIM + cj;
      size_t o1 = (size_t)acts[2 * i2 + 1] * DIM + cj;
      lo2 = w2[o0]; hi2 = w2[o1];
      lo3 = w3[o0]; hi3 = w3[o1];
    }
    Wp2[j * KP2 + i2] = (unsigned)f2bf(lo2) | ((unsigned)f2bf(hi2) << 16);
    Wp3[j * KP2 + i2] = (unsigned)f2bf(lo3) | ((unsigned)f2bf(hi3) << 16);
  }
  __syncthreads();

  const int  j   = t & 127;
  const int  rg  = (t >> 7) & 3;
  const bool jok = j < KACT;

  for (int ch = 0; ch < 4; ++ch) {
    // scatter-compact 16 dense rows into xs
    {
      const size_t base = (size_t)(row0 + ch * 16) * DIM;
      #pragma unroll
      for (int it = 0; it < 4; ++it) {
        int e = t + it * 512;
        int r = e >> 7, c8 = e & 127;
        u16x8 v = *(const u16x8*)(xb + base + (size_t)r * DIM + c8 * 8);
        #pragma unroll
        for (int q = 0; q < 8; ++q) {
          int m = cms[c8 * 8 + q];
          if (m >= 0) xs[r * KPAD + m] = bfasf(((unsigned)(unsigned short)v[q]) << 16);
        }
      }
    }
    __syncthreads();
    // compute: two K=102 dots per output, 4 rows per thread
    if (jok) {
      float a2[4], a3[4];
      #pragma unroll
      for (int r = 0; r < 4; ++r) { a2[r] = 0.f; a3[r] = 0.f; }
      const unsigned int* wp2 = &Wp2[j * KP2];
      const unsigned int* wp3 = &Wp3[j * KP2];
      for (int g = 0; g < 26; ++g) {
        unsigned ua = wp2[2 * g], ub = wp2[2 * g + 1];
        unsigned va = wp3[2 * g], vb = wp3[2 * g + 1];
        float w2v0 = bfasf(ua << 16), w2v1 = bfasf(ua & 0xFFFF0000u);
        float w2v2 = bfasf(ub << 16), w2v3 = bfasf(ub & 0xFFFF0000u);
        float w3v0 = bfasf(va << 16), w3v1 = bfasf(va & 0xFFFF0000u);
        float w3v2 = bfasf(vb << 16), w3v3 = bfasf(vb & 0xFFFF0000u);
        #pragma unroll
        for (int r = 0; r < 4; ++r) {
          f32x4 xv = *(const f32x4*)(&xs[(rg * 4 + r) * KPAD + g * 4]);
          a2[r] += xv[0] * w2v0 + xv[1] * w2v1 + xv[2] * w2v2 + xv[3] * w2v3;
          a3[r] += xv[0] * w3v0 + xv[1] * w3v1 + xv[2] * w3v2 + xv[3] * w3v3;
        }
      }
      #pragma unroll
      for (int r = 0; r < 4; ++r) {
        int rr = rg * 4 + r;
        float g = xs[rr * KPAD + j];
        r2s[rr * KPAD + j] = a2[r] * g;
        r3s[rr * KPAD + j] = a3[r] * a3[r] * g;
      }
    }
    __syncthreads();
    // dense fp32 row writes (float4), zeros at inactive columns
    {
      const int r0 = row0 + ch * 16;
      const int c0 = (t & 255) * 4;
      const int rh = t >> 8;
      const int4 cm = *(const int4*)(&cms[c0]);
      #pragma unroll
      for (int k = 0; k < 8; ++k) {
        int r = rh + k * 2;
        const float* rr2 = &r2s[r * KPAD];
        const float* rr3 = &r3s[r * KPAD];
        float4 o2, o3;
        o2.x = (cm.x >= 0) ? rr2[cm.x] : 0.f;  o3.x = (cm.x >= 0) ? rr3[cm.x] : 0.f;
        o2.y = (cm.y >= 0) ? rr2[cm.y] : 0.f;  o3.y = (cm.y >= 0) ? rr3[cm.y] : 0.f;
        o2.z = (cm.z >= 0) ? rr2[cm.z] : 0.f;  o3.z = (cm.z >= 0) ? rr3[cm.z] : 0.f;
        o2.w = (cm.w >= 0) ? rr2[cm.w] : 0.f;  o3.w = (cm.w >= 0) ? rr3[cm.w] : 0.f;
        size_t oo = (size_t)(r0 + r) * DIM + c0;
        *(float4*)(out2 + oo) = o2;
        *(float4*)(out3 + oo) = o3;
      }
    }
    __syncthreads();
  }
}

// ---------------------------------------------------------------------------
extern "C" void kernel_launch(void* const* d_in, const int* in_sizes, int n_in,
                              void* d_out, int out_size, void* d_ws, size_t ws_size,
                              hipStream_t stream) {
  const float* x  = (const float*)d_in[0];
  const float* w1 = (const float*)d_in[1];
  const float* w2 = (const float*)d_in[2];
  const float* w3 = (const float*)d_in[3];

  float* out1 = (float*)d_out;
  float* out2 = out1 + (size_t)B_ROWS * DIM;
  float* out3 = out2 + (size_t)B_ROWS * DIM;

  char* ws = (char*)d_ws;
  unsigned short* xb     = (unsigned short*)ws;                  // 67108864 B
  unsigned short* w1t    = (unsigned short*)(ws + 67108864);     //  2097152 B
  float*          partial= (float*)(ws + 69206016);              //  2097152 B
  float*          p2     = (float*)(ws + 71303168);              //    32768 B
  int*            cmap   = (int*)(ws + 71335936);                //     4096 B
  int*            act    = (int*)(ws + 71340032);                //      512 B

  k_convw   <<<dim3(768), dim3(256),  0, stream>>>(x, w1, xb, w1t, partial);
  k_reduce1 <<<dim3(64),  dim3(128),  0, stream>>>(partial, p2);
  k_sel     <<<dim3(1),   dim3(1024), 0, stream>>>(p2, act, cmap);
  k_gemm_r1 <<<dim3(512), dim3(512),  0, stream>>>(xb, w1t, out1);
  k_r23     <<<dim3(512), dim3(512),  0, stream>>>(xb, w2, w3, act, cmap, out2, out3);
}

// Round 7
// 254.126 us; speedup vs baseline: 1.0880x; 1.0880x over previous
//
#include <hip/hip_runtime.h>
#include <hip/hip_bf16.h>
#include <stdint.h>

#define B_ROWS 32768
#define DIM    1024
#define KACT   102       // int(1024*0.1)
#define KPAD   104

typedef short bf16x8 __attribute__((ext_vector_type(8)));
typedef unsigned short u16x8 __attribute__((ext_vector_type(8)));
typedef float f32x4  __attribute__((ext_vector_type(4)));

__device__ __forceinline__ unsigned short f2bf(float f) {
  union { float f; unsigned u; } v; v.f = f;
  unsigned u = v.u;
  unsigned r = u + 0x7fffu + ((u >> 16) & 1u);   // RNE
  return (unsigned short)(r >> 16);
}
__device__ __forceinline__ float bfasf(unsigned hi16) {   // f32 from top-16 bits
  union { unsigned u; float f; } v; v.u = hi16;
  return v.f;
}

// async global->LDS, 16B per lane
#define GLDS(g, l) __builtin_amdgcn_global_load_lds( \
    (__attribute__((address_space(1))) void*)(g),    \
    (__attribute__((address_space(3))) void*)(l), 16, 0, 0)

// ---------------------------------------------------------------------------
// K1: merged conv + w1t (verbatim from R5/R6; per-block code == R3).
// ---------------------------------------------------------------------------
__global__ __launch_bounds__(256) void k_convw(
    const float* __restrict__ x, const float* __restrict__ w1,
    unsigned short* __restrict__ xb, unsigned short* __restrict__ w1t,
    float* __restrict__ partial) {
  const int t = threadIdx.x;
  if (blockIdx.x < 512) {
    const int c0 = t * 4;
    const size_t base = (size_t)blockIdx.x * 64 * DIM;
    float s0 = 0.f, s1 = 0.f, s2 = 0.f, s3 = 0.f;
    #pragma unroll 4
    for (int j = 0; j < 64; ++j) {
      size_t off = base + (size_t)j * DIM + c0;
      float4 v = *(const float4*)(x + off);
      s0 += fabsf(v.x); s1 += fabsf(v.y); s2 += fabsf(v.z); s3 += fabsf(v.w);
      ushort4 o;
      o.x = f2bf(v.x); o.y = f2bf(v.y); o.z = f2bf(v.z); o.w = f2bf(v.w);
      *(ushort4*)(xb + off) = o;
    }
    float4 p; p.x = s0; p.y = s1; p.z = s2; p.w = s3;
    *(float4*)(partial + (size_t)blockIdx.x * DIM + c0) = p;
  } else {
    __shared__ unsigned short tile[64][65];
    const int b  = blockIdx.x - 512;
    const int bx = b & 15;
    const int by = b >> 4;
    for (int e = t; e < 64 * 64; e += 256) {
      int r = e >> 6, c = e & 63;
      tile[r][c] = f2bf(w1[(size_t)(by * 64 + r) * DIM + bx * 64 + c]);
    }
    __syncthreads();
    for (int e = t; e < 64 * 64; e += 256) {
      int c = e >> 6, r = e & 63;
      w1t[(size_t)(bx * 64 + c) * DIM + by * 64 + r] = tile[r][c];
    }
  }
}

// ---------------------------------------------------------------------------
// K2: reduce 512 partials -> 8 k-slice partials (deterministic, verbatim).
// ---------------------------------------------------------------------------
__global__ __launch_bounds__(128) void k_reduce1(const float* __restrict__ partial,
                                                 float* __restrict__ p2) {
  const int c  = (blockIdx.x & 7) * 128 + threadIdx.x;
  const int ks = blockIdx.x >> 3;
  float s = 0.f;
  #pragma unroll 8
  for (int p = ks * 64; p < ks * 64 + 64; ++p) s += partial[(size_t)p * DIM + c];
  p2[ks * DIM + c] = s;
}

// ---------------------------------------------------------------------------
// K3: rank + compact (verbatim from R6; rank arithmetic identical to all
// passing rounds).
// ---------------------------------------------------------------------------
__global__ __launch_bounds__(1024) void k_sel(const float* __restrict__ p2,
                                              int* __restrict__ act,
                                              int* __restrict__ cmap) {
  __shared__ double sv[DIM];
  __shared__ int wcnt[16];
  const int d = threadIdx.x;
  {
    double s = 0.0;
    #pragma unroll
    for (int ks = 0; ks < 8; ++ks) s += (double)p2[ks * DIM + d];
    sv[d] = s;
  }
  __syncthreads();
  const double sd = sv[d];
  int rank = 0;
  for (int j = 0; j < DIM; ++j) {
    double s = sv[j];
    rank += (s > sd || (s == sd && j < d)) ? 1 : 0;
  }
  const int f = (rank < KACT) ? 1 : 0;
  unsigned long long m = __ballot(f != 0);
  const int lane = d & 63, w = d >> 6;
  if (lane == 0) wcnt[w] = __popcll(m);
  __syncthreads();
  int off = 0;
  for (int i = 0; i < w; ++i) off += wcnt[i];
  int pos = off + __popcll(m & ((1ull << lane) - 1ull));
  cmap[d] = f ? pos : -1;
  if (f) act[pos] = d;
}

// ---------------------------------------------------------------------------
// K4: gather compact W2sub/W3sub [KPAD][KPAD] fp32 (R3 verbatim; parallel
// 104-block gather, one-shot — NOT per-r23-block).
// ---------------------------------------------------------------------------
__global__ __launch_bounds__(128) void k_wsub(const float* __restrict__ w2,
                                              const float* __restrict__ w3,
                                              const int* __restrict__ act,
                                              float* __restrict__ W2sub,
                                              float* __restrict__ W3sub) {
  const int i = blockIdx.x;
  const int j = threadIdx.x;
  if (j >= KPAD) return;
  float v2 = 0.f, v3 = 0.f;
  if (i < KACT && j < KACT) {
    size_t o = (size_t)act[i] * DIM + act[j];
    v2 = w2[o]; v3 = w3[o];
  }
  W2sub[i * KPAD + j] = v2;
  W3sub[i * KPAD + j] = v3;
}

// ---------------------------------------------------------------------------
// K5: r1 = x @ w1 bf16 MFMA — R3 VERBATIM (best measured). 256x256 tile,
// 8 waves, BK=32, 4-slot ring, 2 phases/K-tile, counted vmcnt(4), setprio,
// XOR bank swizzle, launch_bounds(512,1).
// ---------------------------------------------------------------------------
#define VMW4 asm volatile("s_waitcnt vmcnt(4)" ::: "memory")
#define VMW0 asm volatile("s_waitcnt vmcnt(0)" ::: "memory")
#define NOP_ (void)0

#define STAGE_A(KT) do { \
  GLDS(Abase + (size_t)sr0 * 1024 + (KT) * 32 + sc0 * 8, &Asl[((KT)&3)*8192 + p0*8]); \
  GLDS(Abase + (size_t)sr1 * 1024 + (KT) * 32 + sc1 * 8, &Asl[((KT)&3)*8192 + p1*8]); \
} while (0)
#define STAGE_B(KT) do { \
  GLDS(Bbase + (size_t)sr0 * 1024 + (KT) * 32 + sc0 * 8, &Bsl[((KT)&3)*8192 + p0*8]); \
  GLDS(Bbase + (size_t)sr1 * 1024 + (KT) * 32 + sc1 * 8, &Bsl[((KT)&3)*8192 + p1*8]); \
} while (0)

#define PH0(SLOT, STAGE_STMT) do { \
  _Pragma("unroll") for (int i = 0; i < 4; ++i) \
    areg[i] = *(const bf16x8*)(&Asl[(SLOT)*8192 + aoff0 + i * 512]); \
  _Pragma("unroll") for (int i = 0; i < 4; ++i) \
    breg[i] = *(const bf16x8*)(&Bsl[(SLOT)*8192 + boff0 + i * 512]); \
  STAGE_STMT; \
  __builtin_amdgcn_s_barrier(); \
  __builtin_amdgcn_s_setprio(1); \
  _Pragma("unroll") for (int mi = 0; mi < 4; ++mi) \
  _Pragma("unroll") for (int ni = 0; ni < 4; ++ni) \
    acc[mi][ni] = __builtin_amdgcn_mfma_f32_16x16x32_bf16(areg[mi], breg[ni], acc[mi][ni], 0, 0, 0); \
  __builtin_amdgcn_s_setprio(0); \
  __builtin_amdgcn_s_barrier(); \
} while (0)

#define PH1(SLOT, STAGE_STMT, WAIT_STMT) do { \
  _Pragma("unroll") for (int i = 0; i < 4; ++i) \
    areg[i] = *(const bf16x8*)(&Asl[(SLOT)*8192 + aoff0 + 2048 + i * 512]); \
  STAGE_STMT; \
  WAIT_STMT; \
  __builtin_amdgcn_s_barrier(); \
  __builtin_amdgcn_s_setprio(1); \
  _Pragma("unroll") for (int mi = 0; mi < 4; ++mi) \
  _Pragma("unroll") for (int ni = 0; ni < 4; ++ni) \
    acc[4 + mi][ni] = __builtin_amdgcn_mfma_f32_16x16x32_bf16(areg[mi], breg[ni], acc[4 + mi][ni], 0, 0, 0); \
  __builtin_amdgcn_s_setprio(0); \
  __builtin_amdgcn_s_barrier(); \
} while (0)

__global__ __launch_bounds__(512, 1) void k_gemm_r1(
    const unsigned short* __restrict__ A,
    const unsigned short* __restrict__ Bt,
    float* __restrict__ C) {
  __shared__ unsigned short Asl[4 * 8192];
  __shared__ unsigned short Bsl[4 * 8192];

  const int t    = threadIdx.x;
  const int lane = t & 63;
  const int wave = t >> 6;
  const int wm   = wave >> 2;
  const int wn   = wave & 3;
  const int la   = lane & 15;
  const int kg   = lane >> 4;
  const int kgx  = kg ^ ((la >> 1) & 3);

  const int swz  = (blockIdx.x & 7) * 64 + (blockIdx.x >> 3);
  const int brow = swz >> 2;
  const int bcol = swz & 3;

  const unsigned short* Abase = A  + (size_t)brow * 256 * 1024;
  const unsigned short* Bbase = Bt + (size_t)bcol * 256 * 1024;

  const int p0 = t, p1 = t + 512;
  const int q0 = p0 ^ ((p0 >> 3) & 3);
  const int q1 = p1 ^ ((p1 >> 3) & 3);
  const int sr0 = q0 >> 2, sc0 = q0 & 3;
  const int sr1 = q1 >> 2, sc1 = q1 & 3;

  const int aoff0 = (wm * 128 + la) * 32 + kgx * 8;
  const int boff0 = (wn * 64  + la) * 32 + kgx * 8;

  f32x4 acc[8][4];
  #pragma unroll
  for (int mi = 0; mi < 8; ++mi)
    #pragma unroll
    for (int ni = 0; ni < 4; ++ni)
      acc[mi][ni] = (f32x4){0.f, 0.f, 0.f, 0.f};

  bf16x8 areg[4], breg[4];

  STAGE_A(0); STAGE_B(0); STAGE_A(1); STAGE_B(1);
  VMW4;
  __builtin_amdgcn_s_barrier();

  for (int kt4 = 0; kt4 < 28; kt4 += 4) {
    PH0(0, STAGE_A(kt4 + 2)); PH1(0, STAGE_B(kt4 + 2), VMW4);
    PH0(1, STAGE_A(kt4 + 3)); PH1(1, STAGE_B(kt4 + 3), VMW4);
    PH0(2, STAGE_A(kt4 + 4)); PH1(2, STAGE_B(kt4 + 4), VMW4);
    PH0(3, STAGE_A(kt4 + 5)); PH1(3, STAGE_B(kt4 + 5), VMW4);
  }
  PH0(0, STAGE_A(30)); PH1(0, STAGE_B(30), VMW4);
  PH0(1, STAGE_A(31)); PH1(1, STAGE_B(31), VMW4);
  PH0(2, NOP_);        PH1(2, NOP_, VMW0);
  PH0(3, NOP_);        PH1(3, NOP_, NOP_);

  const int orow0 = brow * 256 + wm * 128 + (lane >> 4) * 4;
  const int ocol0 = bcol * 256 + wn * 64 + la;
  #pragma unroll
  for (int mi = 0; mi < 8; ++mi)
    #pragma unroll
    for (int ni = 0; ni < 4; ++ni)
      #pragma unroll
      for (int r = 0; r < 4; ++r)
        C[(size_t)(orow0 + mi * 16 + r) * DIM + ocol0 + ni * 16] = acc[mi][ni][r];
}

// ---------------------------------------------------------------------------
// K6: r2/r3 — R3 structure VERBATIM (256 blocks x 512 thr, 128 rows/block,
// fp32 W2s/W3s in LDS, double-buffered xs ping-pong with reg prefetch,
// launch_bounds(512) only). SINGLE CHANGE vs R3: input is xb (bf16),
// loads are u16x8, unpack folded into the XSW scatter.
// ---------------------------------------------------------------------------
__global__ __launch_bounds__(512) void k_r23(
    const unsigned short* __restrict__ xb,
    const float* __restrict__ W2sub,
    const float* __restrict__ W3sub,
    const int* __restrict__ cmap,
    float* __restrict__ out2,
    float* __restrict__ out3) {
  __shared__ float W2s[KPAD * KPAD];
  __shared__ float W3s[KPAD * KPAD];
  __shared__ float xs[2][16 * KPAD];
  __shared__ float r2s[16 * KPAD];
  __shared__ float r3s[16 * KPAD];
  __shared__ int   cms[DIM];
  const int t    = threadIdx.x;
  const int row0 = blockIdx.x * 128;

  for (int e = t; e < KPAD * KPAD; e += 512) { W2s[e] = W2sub[e]; W3s[e] = W3sub[e]; }
  for (int e = t; e < DIM; e += 512) cms[e] = cmap[e];
  for (int e = t; e < 2 * 16 * KPAD; e += 512) ((float*)xs)[e] = 0.f;
  __syncthreads();

  const int  j   = t & 127;
  const int  rg  = (t >> 7) & 3;
  const bool jok = j < KACT;

  auto LOADR = [&](int ch, u16x8* ld) {
    const size_t base = (size_t)(row0 + ch * 16) * DIM;
    #pragma unroll
    for (int it = 0; it < 4; ++it) {
      int e = t + it * 512;
      int r = e >> 7, c8 = e & 127;
      ld[it] = *(const u16x8*)(xb + base + (size_t)r * DIM + c8 * 8);
    }
  };
  auto XSW = [&](int buf, const u16x8* ld) {
    #pragma unroll
    for (int it = 0; it < 4; ++it) {
      int e = t + it * 512;
      int r = e >> 7, c8 = e & 127;
      #pragma unroll
      for (int q = 0; q < 8; ++q) {
        int m = cms[c8 * 8 + q];
        if (m >= 0) xs[buf][r * KPAD + m] = bfasf(((unsigned)(unsigned short)ld[it][q]) << 16);
      }
    }
  };
  auto COMPUTE = [&](int buf) {
    if (jok) {
      float a2[4], a3[4];
      #pragma unroll
      for (int r = 0; r < 4; ++r) { a2[r] = 0.f; a3[r] = 0.f; }
      for (int i = 0; i < KPAD; i += 4) {
        float w2v[4], w3v[4];
        #pragma unroll
        for (int q = 0; q < 4; ++q) {
          w2v[q] = W2s[(i + q) * KPAD + j];
          w3v[q] = W3s[(i + q) * KPAD + j];
        }
        #pragma unroll
        for (int r = 0; r < 4; ++r) {
          f32x4 xv = *(const f32x4*)(&xs[buf][(rg * 4 + r) * KPAD + i]);
          a2[r] += xv[0] * w2v[0] + xv[1] * w2v[1] + xv[2] * w2v[2] + xv[3] * w2v[3];
          a3[r] += xv[0] * w3v[0] + xv[1] * w3v[1] + xv[2] * w3v[2] + xv[3] * w3v[3];
        }
      }
      #pragma unroll
      for (int r = 0; r < 4; ++r) {
        int rr = rg * 4 + r;
        float g = xs[buf][rr * KPAD + j];
        r2s[rr * KPAD + j] = a2[r] * g;
        r3s[rr * KPAD + j] = a3[r] * a3[r] * g;
      }
    }
  };
  auto WRITEOUT = [&](int ch) {
    const int r0 = row0 + ch * 16;
    const int c0 = (t & 255) * 4;
    const int rh = t >> 8;
    const int4 cm = *(const int4*)(&cms[c0]);
    #pragma unroll
    for (int k = 0; k < 8; ++k) {
      int r = rh + k * 2;
      const float* rr2 = &r2s[r * KPAD];
      const float* rr3 = &r3s[r * KPAD];
      float4 o2, o3;
      o2.x = (cm.x >= 0) ? rr2[cm.x] : 0.f;  o3.x = (cm.x >= 0) ? rr3[cm.x] : 0.f;
      o2.y = (cm.y >= 0) ? rr2[cm.y] : 0.f;  o3.y = (cm.y >= 0) ? rr3[cm.y] : 0.f;
      o2.z = (cm.z >= 0) ? rr2[cm.z] : 0.f;  o3.z = (cm.z >= 0) ? rr3[cm.z] : 0.f;
      o2.w = (cm.w >= 0) ? rr2[cm.w] : 0.f;  o3.w = (cm.w >= 0) ? rr3[cm.w] : 0.f;
      size_t oo = (size_t)(r0 + r) * DIM + c0;
      *(float4*)(out2 + oo) = o2;
      *(float4*)(out3 + oo) = o3;
    }
  };

  u16x8 ldA[4], ldB[4];
  LOADR(0, ldA);
  XSW(0, ldA);
  __syncthreads();
  for (int ch2 = 0; ch2 < 8; ch2 += 2) {
    if (ch2 + 1 < 8) LOADR(ch2 + 1, ldB);
    COMPUTE(0);
    __syncthreads();
    WRITEOUT(ch2);
    if (ch2 + 1 < 8) XSW(1, ldB);
    __syncthreads();
    if (ch2 + 2 < 8) LOADR(ch2 + 2, ldA);
    COMPUTE(1);
    __syncthreads();
    WRITEOUT(ch2 + 1);
    if (ch2 + 2 < 8) XSW(0, ldA);
    __syncthreads();
  }
}

// ---------------------------------------------------------------------------
extern "C" void kernel_launch(void* const* d_in, const int* in_sizes, int n_in,
                              void* d_out, int out_size, void* d_ws, size_t ws_size,
                              hipStream_t stream) {
  const float* x  = (const float*)d_in[0];
  const float* w1 = (const float*)d_in[1];
  const float* w2 = (const float*)d_in[2];
  const float* w3 = (const float*)d_in[3];

  float* out1 = (float*)d_out;
  float* out2 = out1 + (size_t)B_ROWS * DIM;
  float* out3 = out2 + (size_t)B_ROWS * DIM;

  char* ws = (char*)d_ws;
  unsigned short* xb     = (unsigned short*)ws;                  // 67108864 B
  unsigned short* w1t    = (unsigned short*)(ws + 67108864);     //  2097152 B
  float*          partial= (float*)(ws + 69206016);              //  2097152 B
  float*          p2     = (float*)(ws + 71303168);              //    32768 B
  int*            cmap   = (int*)(ws + 71335936);                //     4096 B
  int*            act    = (int*)(ws + 71340032);                //      512 B
  float*          W2sub  = (float*)(ws + 71340544);              //    43264 B
  float*          W3sub  = (float*)(ws + 71383808);              //    43264 B

  k_convw   <<<dim3(768),  dim3(256),  0, stream>>>(x, w1, xb, w1t, partial);
  k_reduce1 <<<dim3(64),   dim3(128),  0, stream>>>(partial, p2);
  k_sel     <<<dim3(1),    dim3(1024), 0, stream>>>(p2, act, cmap);
  k_wsub    <<<dim3(KPAD), dim3(128),  0, stream>>>(w2, w3, act, W2sub, W3sub);
  k_gemm_r1 <<<dim3(512),  dim3(512),  0, stream>>>(xb, w1t, out1);
  k_r23     <<<dim3(256),  dim3(512),  0, stream>>>(xb, W2sub, W3sub, cmap, out2, out3);
}